// Round 1
// 1022.411 us; speedup vs baseline: 1.5671x; 1.5671x over previous
//
#include <hip/hip_runtime.h>
#include <hip/hip_bf16.h>

typedef __hip_bfloat16 bf16;
typedef unsigned short u16;
typedef unsigned int u32;
typedef __attribute__((ext_vector_type(8))) short s8b;     // 8 bf16 = 4 VGPR MFMA frag
typedef __attribute__((ext_vector_type(4))) float f32x4;   // MFMA accum

#define EPSF 1e-8f

// ---------------------------------------------------------------------------
// Static device buffers (module-load allocated; no ws_size dependence):
//   g_wpack : bf16 hi/lo MFMA-B fragments for all 9 weight matrices, chunked
//             1024B per (ks, ntile, split), lane-contiguous (dwordx4/lane).
//   g_bias  : all 9 bias vectors as f32.
//   g_T*    : images transposed to (b,y,x,c) f32 for coalesced sampling.
// d_ws keeps only the old small region: P matrices, dtype flag, image stats.
// ---------------------------------------------------------------------------
__device__ __align__(16) u16 g_wpack[430080];  // 860160 bytes
__device__ float g_bias[1344];
__device__ float g_T0[2 * 64 * 64 * 64];
__device__ float g_T1[2 * 128 * 32 * 32];
__device__ float g_T2[2 * 256 * 16 * 16];

// ---- scalar load/store helpers --------------------------------------------
__device__ __forceinline__ float ldf(const void* p, size_t i, int f32v) {
  return f32v ? ((const float*)p)[i] : __bfloat162float(((const bf16*)p)[i]);
}
__device__ __forceinline__ void stf(void* p, size_t i, float v, int f32v) {
  if (f32v) ((float*)p)[i] = v;
  else ((bf16*)p)[i] = __float2bfloat16(v);
}
template <bool F32>
__device__ __forceinline__ float ld(const void* p, size_t i) {
  if constexpr (F32) return ((const float*)p)[i];
  else return __bfloat162float(((const bf16*)p)[i]);
}

// hi/lo bf16 split: v ~= hi + lo with ~2^-16 relative error
__device__ __forceinline__ void splitbf(float v, u16& h, u16& l) {
  bf16 hb = __float2bfloat16(v);
  float hf = __bfloat162float(hb);
  bf16 lb = __float2bfloat16(v - hf);
  h = __builtin_bit_cast(u16, hb);
  l = __builtin_bit_cast(u16, lb);
}
__device__ __forceinline__ float bfjoin(u16 h, u16 l) {
  return __uint_as_float((u32)h << 16) + __uint_as_float((u32)l << 16);
}

// LDS activation tile: [32 rows][256 cols] bf16, row stride 512B,
// XOR-swizzled (G4: byte ^= (row&7)<<4) so 16-row b128 column reads are
// conflict-free. col must be a multiple of 8 for 16B vector access.
__device__ __forceinline__ u16* xaddr(u16* base, int row, int col) {
  int byte = (row << 9) + (col << 1);
  byte ^= (row & 7) << 4;
  return (u16*)((char*)base + byte);
}
__device__ __forceinline__ const u16* xaddrc(const u16* base, int row, int col) {
  int byte = (row << 9) + (col << 1);
  byte ^= (row & 7) << 4;
  return (const u16*)((const char*)base + byte);
}

__device__ __forceinline__ f32x4 MFMA(s8b a, s8b b, f32x4 c) {
  return __builtin_amdgcn_mfma_f32_16x16x32_bf16(a, b, c, 0, 0, 0);
}

// ---------------------------------------------------------------------------
// dtype detect: extrinsic[0] == 1.0 + noise(0.01) read as f32
__global__ void detect_kernel(const void* extr, int* flag) {
  if (threadIdx.x == 0 && blockIdx.x == 0) {
    float v = ((const float*)extr)[0];
    *flag = (fabsf(v - 1.0f) < 0.25f) ? 1 : 0;
  }
}

// ---- image stats + P matrices (unchanged from previous version) -----------
template <bool F32>
__device__ void stats_body(const void* img0, const void* img1, const void* img2,
                           const void* intr, const void* extr,
                           float* wsf, float* red) {
  int bid = blockIdx.x;
  if (bid >= 896) {
    int b = bid - 896;
    int t = threadIdx.x;
    if (t < 12) {
      int r = t >> 2, c = t & 3;
      float acc = 0.f;
      for (int k = 0; k < 3; ++k)
        acc += ld<F32>(intr, b * 9 + r * 3 + k) * ld<F32>(extr, b * 12 + k * 4 + c);
      wsf[b * 12 + r * 4 + c] = acc;
    }
    return;
  }
  const void* src; size_t base; int HW, outidx;
  if (bid < 128) {
    int b = bid >> 6, c = bid & 63;
    src = img0; base = (size_t)(b * 64 + c) * 4096; HW = 4096;
    outidx = 32 + b * 64 + c;
  } else if (bid < 384) {
    int t = bid - 128; int b = t >> 7, c = t & 127;
    src = img1; base = (size_t)(b * 128 + c) * 1024; HW = 1024;
    outidx = 32 + 128 + b * 128 + c;
  } else {
    int t = bid - 384; int b = t >> 8, c = t & 255;
    src = img2; base = (size_t)(b * 256 + c) * 256; HW = 256;
    outidx = 32 + 384 + b * 256 + c;
  }
  float s1 = 0.f, s2 = 0.f;
  for (int i = threadIdx.x; i < HW; i += 256) {
    float v = ld<F32>(src, base + i);
    s1 += v; s2 += v * v;
  }
  for (int off = 32; off; off >>= 1) {
    s1 += __shfl_xor(s1, off);
    s2 += __shfl_xor(s2, off);
  }
  int wid = threadIdx.x >> 6, lane = threadIdx.x & 63;
  if (lane == 0) { red[wid] = s1; red[4 + wid] = s2; }
  __syncthreads();
  if (threadIdx.x == 0) {
    float S1 = red[0] + red[1] + red[2] + red[3];
    float S2 = red[4] + red[5] + red[6] + red[7];
    float mu = S1 / (float)HW;
    float var = (S2 - (float)HW * mu * mu) / (float)(HW - 1);
    var = fmaxf(var, 0.f);
    wsf[outidx] = mu;
    wsf[outidx + 896] = sqrtf(var + EPSF);
  }
}

__global__ __launch_bounds__(256) void stats_kernel(
    const void* img0, const void* img1, const void* img2,
    const void* intr, const void* extr, float* wsf, const int* flag) {
  __shared__ float red[8];
  if (*flag) stats_body<true>(img0, img1, img2, intr, extr, wsf, red);
  else       stats_body<false>(img0, img1, img2, intr, extr, wsf, red);
}

// ---- (B,C,H,W) -> (B,H,W,C) f32 into static arrays ------------------------
__global__ __launch_bounds__(256) void transpose_kernel(
    const void* src, int which, int C, int R, const int* flag) {
  float* dst = (which == 0) ? g_T0 : (which == 1) ? g_T1 : g_T2;
  const int f32v = *flag;
  int total = 2 * C * R * R;
  for (int i = blockIdx.x * 256 + threadIdx.x; i < total; i += gridDim.x * 256) {
    int c = i % C; int t = i / C;
    int x = t % R; t /= R;
    int y = t % R; int b = t / R;
    dst[i] = ldf(src, ((size_t)(b * C + c) * R + y) * R + x, f32v);
  }
}

// ---- weight/bias packing ---------------------------------------------------
// Layer order: w1_0,w2_0,fcw_0, w1_1,w2_1,fcw_1, w1_2,w2_2,fcw_2
// Per layer: chunks enumerated as ((ks*(COUT/16) + ntile)*2 + split)*1024B.
// Chunk content: lane l, elem j -> W[ks*32 + (l>>4)*8 + j][ntile*16 + (l&15)]
// (split 0 = bf16 hi, split 1 = bf16 lo). Zero-padded past K_real.
__global__ __launch_bounds__(256) void pack_kernel(
    const void* w0, const void* w1, const void* w2, const void* w3,
    const void* w4, const void* w5, const void* w6, const void* w7,
    const void* w8,
    const void* bb0, const void* bb1, const void* bb2, const void* bb3,
    const void* bb4, const void* bb5, const void* bb6, const void* bb7,
    const void* bb8, const int* flag) {
  const int f32v = *flag;
  int gid = blockIdx.x * 256 + threadIdx.x;
  int chunk = gid >> 6, lane = gid & 63;
  if (chunk < 840) {
    const int nch[9]   = {8, 16, 16, 32, 64, 64, 128, 256, 256};
    const int couts[9] = {64, 64, 64, 128, 128, 128, 256, 256, 256};
    const int kreal[9] = {3, 64, 64, 64, 128, 128, 128, 256, 256};
    const void* wp[9] = {w0, w1, w2, w3, w4, w5, w6, w7, w8};
    int layer = 0, start = 0;
    while (chunk >= start + nch[layer]) { start += nch[layer]; ++layer; }
    int ci = chunk - start;
    int COUT = couts[layer];
    int ntc = COUT >> 4;
    int ks = ci / (ntc * 2);
    int rem = ci % (ntc * 2);
    int ntile = rem >> 1, split = rem & 1;
    const void* W = wp[layer];
    int KR = kreal[layer];
    s8b sv;
#pragma unroll
    for (int j = 0; j < 8; ++j) {
      int k = ks * 32 + (lane >> 4) * 8 + j;
      int c = ntile * 16 + (lane & 15);
      float v = (k < KR) ? ldf(W, (size_t)k * COUT + c, f32v) : 0.f;
      u16 h, l; splitbf(v, h, l);
      sv[j] = (short)(split == 0 ? h : l);
    }
    *(s8b*)&g_wpack[(size_t)chunk * 512 + lane * 8] = sv;
  } else {
    int t = gid - 840 * 64;
    if (t < 1344) {
      const int off[9] = {0, 64, 128, 192, 320, 448, 576, 832, 1088};
      const void* bp[9] = {bb0, bb1, bb2, bb3, bb4, bb5, bb6, bb7, bb8};
      int seg = 0;
      while (seg < 8 && t >= off[seg + 1]) ++seg;
      g_bias[t] = ldf(bp[seg], t - off[seg], f32v);
    }
  }
}

// ---------------------------------------------------------------------------
// MFMA accumulate: out[32 x COUT] += X[32 x KS*32] @ W  (hi/lo split, 3 MFMA)
// wave wid: mtile = wid&1 (16 rows), nstrip = wid>>1 (COUT/2 cols).
// ---------------------------------------------------------------------------
template <int KS, int COUT>
__device__ __forceinline__ void mm_acc(
    const u16* Ph, const u16* Pl, int wbase, int bbase, int tid,
    f32x4 (&acc)[COUT / 32]) {
  constexpr int NT = COUT / 32;
  int lane = tid & 63, wid = tid >> 6;
  int mt = wid & 1;
  int nt0 = (wid >> 1) * NT;
  int colc = lane & 15;
#pragma unroll
  for (int n = 0; n < NT; ++n) {
    float bv = g_bias[bbase + (nt0 + n) * 16 + colc];
    acc[n] = (f32x4){bv, bv, bv, bv};
  }
  int rowA = mt * 16 + (lane & 15);
  int koff = (lane >> 4) * 8;
  const char* wp = (const char*)g_wpack + wbase + lane * 16;
#pragma unroll
  for (int ks = 0; ks < KS; ++ks) {
    s8b ah = *(const s8b*)xaddrc(Ph, rowA, ks * 32 + koff);
    s8b al = *(const s8b*)xaddrc(Pl, rowA, ks * 32 + koff);
#pragma unroll
    for (int n = 0; n < NT; ++n) {
      int ch = (ks * (COUT / 16) + nt0 + n) * 2048;
      s8b bh = *(const s8b*)(wp + ch);
      s8b bl = *(const s8b*)(wp + ch + 1024);
      acc[n] = MFMA(al, bh, acc[n]);
      acc[n] = MFMA(ah, bl, acc[n]);
      acc[n] = MFMA(ah, bh, acc[n]);
    }
  }
}

// dense layer -> LDS (relu), hi/lo bf16 output
template <int KS, int COUT>
__device__ __forceinline__ void dense_mfma(
    const u16* Ph, const u16* Pl, u16* Qh, u16* Ql,
    int wbase, int bbase, int tid) {
  constexpr int NT = COUT / 32;
  f32x4 acc[NT];
  mm_acc<KS, COUT>(Ph, Pl, wbase, bbase, tid, acc);
  int lane = tid & 63, wid = tid >> 6;
  int mt = wid & 1;
  int nt0 = (wid >> 1) * NT;
  int colc = lane & 15;
  int r0 = mt * 16 + (lane >> 4) * 4;
#pragma unroll
  for (int n = 0; n < NT; ++n) {
    int c = (nt0 + n) * 16 + colc;
#pragma unroll
    for (int q = 0; q < 4; ++q) {
      float v = fmaxf(acc[n][q], 0.f);
      u16 h, l; splitbf(v, h, l);
      *xaddr(Qh, r0 + q, c) = h;
      *xaddr(Ql, r0 + q, c) = l;
    }
  }
}

// fc layer -> global out
template <int KS, int COUT>
__device__ __forceinline__ void fc_mfma(
    const u16* Ph, const u16* Pl, int wbase, int bbase,
    void* out, u32 colbase, u32 R0, int f32v, int tid) {
  constexpr int NT = COUT / 32;
  f32x4 acc[NT];
  mm_acc<KS, COUT>(Ph, Pl, wbase, bbase, tid, acc);
  int lane = tid & 63, wid = tid >> 6;
  int mt = wid & 1;
  int nt0 = (wid >> 1) * NT;
  int colc = lane & 15;
  u32 grow0 = R0 + mt * 16 + (lane >> 4) * 4;
  if (f32v) {
#pragma unroll
    for (int n = 0; n < NT; ++n) {
      u32 c = colbase + (nt0 + n) * 16 + colc;
#pragma unroll
      for (int q = 0; q < 4; ++q)
        ((float*)out)[(grow0 + q) * 899u + c] = acc[n][q];
    }
  } else {
#pragma unroll
    for (int n = 0; n < NT; ++n) {
      u32 c = colbase + (nt0 + n) * 16 + colc;
#pragma unroll
      for (int q = 0; q < 4; ++q)
        ((bf16*)out)[(grow0 + q) * 899u + c] = __float2bfloat16(acc[n][q]);
    }
  }
}

// ---- AdaIN: per-row mean/var over C, normalize + image stats --------------
// wave handles 8 rows; 8 lanes per row, each lane C/8 consecutive channels.
template <int C>
__device__ __forceinline__ void adain_mfma(
    const u16* Ph, const u16* Pl, u16* Qh, u16* Ql,
    const float* meanw, const float* sigw, int b, int tid) {
  constexpr int CH = C / 8;
  int lane = tid & 63, wid = tid >> 6;
  int row = wid * 8 + (lane >> 3);
  int c0 = (lane & 7) * CH;
  float v[CH];
  float s1 = 0.f, s2 = 0.f;
#pragma unroll
  for (int k = 0; k < CH; k += 8) {
    s8b h = *(const s8b*)xaddrc(Ph, row, c0 + k);
    s8b l = *(const s8b*)xaddrc(Pl, row, c0 + k);
#pragma unroll
    for (int i = 0; i < 8; ++i) {
      float f = bfjoin((u16)h[i], (u16)l[i]);
      v[k + i] = f; s1 += f; s2 += f * f;
    }
  }
#pragma unroll
  for (int off = 1; off < 8; off <<= 1) {
    s1 += __shfl_xor(s1, off);
    s2 += __shfl_xor(s2, off);
  }
  float mu = s1 / (float)C;
  float var = (s2 - (float)C * mu * mu) / (float)(C - 1);
  var = fmaxf(var, 0.f);
  float rs = 1.0f / sqrtf(var + EPSF);
#pragma unroll
  for (int k = 0; k < CH; k += 8) {
    s8b hv, lv;
#pragma unroll
    for (int i = 0; i < 8; ++i) {
      int cc = c0 + k + i;
      float y = ((v[k + i] - mu) * rs + meanw[b * C + cc]) * sigw[b * C + cc];
      u16 hh, ll; splitbf(y, hh, ll);
      hv[i] = (short)hh; lv[i] = (short)ll;
    }
    *(s8b*)xaddr(Qh, row, c0 + k) = hv;
    *(s8b*)xaddr(Ql, row, c0 + k) = lv;
  }
}

// ---- bilinear border sample of one point from transposed image ------------
template <int C, int R>
__device__ __forceinline__ void sample(
    const float* T, float u, float v, int b, int lane,
    void* out, u32 obase, int f32v) {
  constexpr int J = C / 64;
  float ix = fminf(fmaxf((u + 1.f) * 0.5f * (float)(R - 1), 0.f), (float)(R - 1));
  float iy = fminf(fmaxf((v + 1.f) * 0.5f * (float)(R - 1), 0.f), (float)(R - 1));
  float x0f = floorf(ix), y0f = floorf(iy);
  float wx = ix - x0f, wy = iy - y0f;
  int x0 = (int)x0f, y0 = (int)y0f;
  int x1 = min(x0 + 1, R - 1), y1 = min(y0 + 1, R - 1);
  float w00 = (1.f - wx) * (1.f - wy), w01 = wx * (1.f - wy);
  float w10 = (1.f - wx) * wy,         w11 = wx * wy;
  const float* T00 = T + (size_t)((b * R + y0) * R + x0) * C;
  const float* T01 = T + (size_t)((b * R + y0) * R + x1) * C;
  const float* T10 = T + (size_t)((b * R + y1) * R + x0) * C;
  const float* T11 = T + (size_t)((b * R + y1) * R + x1) * C;
  float sv[J];
#pragma unroll
  for (int j = 0; j < J; ++j) {
    int c = lane + 64 * j;
    sv[j] = T00[c] * w00 + T01[c] * w01 + T10[c] * w10 + T11[c] * w11;
  }
  if (f32v) {
#pragma unroll
    for (int j = 0; j < J; ++j)
      ((float*)out)[obase + lane + 64 * j] = sv[j];
  } else {
#pragma unroll
    for (int j = 0; j < J; ++j)
      ((bf16*)out)[obase + lane + 64 * j] = __float2bfloat16(sv[j]);
  }
}

// ---- projection phase: wave handles 8 points, lane owns channels ----------
__device__ void projection(const void* init_pc, const float* wsf, void* out,
                           u32 R0, int b, int f32v, int tid) {
  int lane = tid & 63, wid = tid >> 6;
  float Pm[12];
#pragma unroll
  for (int i = 0; i < 12; ++i) Pm[i] = wsf[b * 12 + i];
  for (int p = 0; p < 8; ++p) {
    u32 n = R0 + wid * 8 + p;
    float px = ldf(init_pc, (size_t)n * 3 + 0, f32v);
    float py = ldf(init_pc, (size_t)n * 3 + 1, f32v);
    float pz = ldf(init_pc, (size_t)n * 3 + 2, f32v);
    float X = Pm[0] * px + Pm[1] * py + Pm[2] * pz + Pm[3];
    float Y = Pm[4] * px + Pm[5] * py + Pm[6] * pz + Pm[7];
    float Z = Pm[8] * px + Pm[9] * py + Pm[10] * pz + Pm[11];
    float u = -X / Z, vv = Y / Z;
    u32 rowb = n * 899u;
    sample<64, 64>(g_T0, u, vv, b, lane, out, rowb + 448, f32v);
    sample<128, 32>(g_T1, u, vv, b, lane, out, rowb + 512, f32v);
    sample<256, 16>(g_T2, u, vv, b, lane, out, rowb + 640, f32v);
    if (lane < 3) {
      float pv = (lane == 0) ? px : (lane == 1) ? py : pz;
      stf(out, rowb + 896 + lane, pv, f32v);
    }
  }
}

// ---------------------------------------------------------------------------
// Main fused kernel: 32 points/block, 4 waves. Activations ping-pong between
// two LDS hi/lo bf16 tiles; all matmuls via hi/lo-split bf16 MFMA (3 mfma).
// ---------------------------------------------------------------------------
__global__ __launch_bounds__(256, 2) void pce_main(
    const void* init_pc, const float* wsf, const int* flag, void* out) {
  __shared__ u16 Xh[2][32][256];
  __shared__ u16 Xl[2][32][256];
  const int f32v = *flag;
  const int tid = threadIdx.x;
  const u32 R0 = blockIdx.x * 32;
  const int b = R0 >> 16;

  u16* X0h = &Xh[0][0][0]; u16* X0l = &Xl[0][0][0];
  u16* X1h = &Xh[1][0][0]; u16* X1l = &Xl[1][0][0];

  // ---- stage X0 = [px,py,pz,0...] (32 rows x 32 cols, hi/lo) ----
  for (int i = tid; i < 1024; i += 256) {
    int r = i >> 5, c = i & 31;
    *xaddr(X0h, r, c) = 0;
    *xaddr(X0l, r, c) = 0;
  }
  __syncthreads();
  if (tid < 96) {
    int r = tid / 3, c = tid % 3;
    float v = ldf(init_pc, (size_t)(R0 + r) * 3 + c, f32v);
    u16 h, l; splitbf(v, h, l);
    *xaddr(X0h, r, c) = h;
    *xaddr(X0l, r, c) = l;
  }
  __syncthreads();

  // ---- block 0 (64ch) ----
  dense_mfma<1, 64>(X0h, X0l, X1h, X1l, 0, 0, tid);          __syncthreads();
  dense_mfma<2, 64>(X1h, X1l, X0h, X0l, 8192, 64, tid);      __syncthreads();
  adain_mfma<64>(X0h, X0l, X1h, X1l, wsf + 32, wsf + 928, b, tid); __syncthreads();
  fc_mfma<2, 64>(X1h, X1l, 24576, 128, out, 0, R0, f32v, tid);     __syncthreads();

  // ---- block 1 (128ch) ----
  dense_mfma<2, 128>(X0h, X0l, X1h, X1l, 40960, 192, tid);   __syncthreads();
  dense_mfma<4, 128>(X1h, X1l, X0h, X0l, 73728, 320, tid);   __syncthreads();
  adain_mfma<128>(X0h, X0l, X1h, X1l, wsf + 32 + 128, wsf + 928 + 128, b, tid); __syncthreads();
  fc_mfma<4, 128>(X1h, X1l, 139264, 448, out, 64, R0, f32v, tid);  __syncthreads();

  // ---- block 2 (256ch) ----
  dense_mfma<4, 256>(X0h, X0l, X1h, X1l, 204800, 576, tid);  __syncthreads();
  dense_mfma<8, 256>(X1h, X1l, X0h, X0l, 335872, 832, tid);  __syncthreads();
  adain_mfma<256>(X0h, X0l, X1h, X1l, wsf + 32 + 384, wsf + 928 + 384, b, tid); __syncthreads();
  fc_mfma<8, 256>(X1h, X1l, 598016, 1088, out, 192, R0, f32v, tid);

  // ---- projections + passthrough (no LDS; no barrier needed) ----
  projection(init_pc, wsf, out, R0, b, f32v, tid);
}

// ---------------------------------------------------------------------------
extern "C" void kernel_launch(void* const* d_in, const int* in_sizes, int n_in,
                              void* d_out, int out_size, void* d_ws, size_t ws_size,
                              hipStream_t stream) {
  const void* init_pc = d_in[0];
  const void* extr    = d_in[1];
  const void* intr    = d_in[2];
  const void* img0    = d_in[3];
  const void* img1    = d_in[4];
  const void* img2    = d_in[5];
  const void* w1_0 = d_in[6],  *b1_0 = d_in[7];
  const void* w2_0 = d_in[8],  *b2_0 = d_in[9];
  const void* fcw_0 = d_in[10], *fcb_0 = d_in[11];
  const void* w1_1 = d_in[12], *b1_1 = d_in[13];
  const void* w2_1 = d_in[14], *b2_1 = d_in[15];
  const void* fcw_1 = d_in[16], *fcb_1 = d_in[17];
  const void* w1_2 = d_in[18], *b1_2 = d_in[19];
  const void* w2_2 = d_in[20], *b2_2 = d_in[21];
  const void* fcw_2 = d_in[22], *fcb_2 = d_in[23];

  float* wsf = (float*)d_ws;
  int* flagp = (int*)((char*)d_ws + 96);

  detect_kernel<<<1, 1, 0, stream>>>(extr, flagp);
  stats_kernel<<<898, 256, 0, stream>>>(img0, img1, img2, intr, extr, wsf, flagp);
  transpose_kernel<<<2048, 256, 0, stream>>>(img0, 0, 64, 64, flagp);
  transpose_kernel<<<1024, 256, 0, stream>>>(img1, 1, 128, 32, flagp);
  transpose_kernel<<<512, 256, 0, stream>>>(img2, 2, 256, 16, flagp);
  pack_kernel<<<216, 256, 0, stream>>>(
      w1_0, w2_0, fcw_0, w1_1, w2_1, fcw_1, w1_2, w2_2, fcw_2,
      b1_0, b2_0, fcb_0, b1_1, b2_1, fcb_1, b1_2, b2_2, fcb_2, flagp);
  pce_main<<<4096, 256, 0, stream>>>(init_pc, wsf, flagp, d_out);
}

// Round 2
// 900.894 us; speedup vs baseline: 1.7785x; 1.1349x over previous
//
#include <hip/hip_runtime.h>
#include <hip/hip_bf16.h>

typedef __hip_bfloat16 bf16;
typedef unsigned short u16;
typedef unsigned int u32;
typedef __attribute__((ext_vector_type(8))) short s8b;     // 8 bf16 = 4 VGPR MFMA frag
typedef __attribute__((ext_vector_type(16))) float f32x16; // 32x32 MFMA accum

#define EPSF 1e-8f

// ---------------------------------------------------------------------------
// Static device buffers:
//   g_wpack : non-fc dense weights, bf16 hi/lo 32x32x16 B-fragments.
//             chunk = ((ks*(COUT/32)+nt)*2+split)*1024B; lane l elem j holds
//             W[ks*16 + 8*(l>>5) + j][nt*32 + (l&31)].
//   g_fcpack: fc' = diag(sigma_img)*fcw, per-batch (2 copies), same layout.
//   g_bias  : dense biases (896 f32). fc biases folded into g_fcC.
//   g_fcS   : [2][448] colsum_j(W')      (AdaIN fold)
//   g_fcC   : [2][448] imean@W' + fcb    (AdaIN fold)
//   g_T*    : images transposed to (b,y,x,c) f32.
// ---------------------------------------------------------------------------
__device__ __align__(16) u16 g_wpack[256000];   // 500 chunks
__device__ __align__(16) u16 g_fcpack[344064];  // 672 chunks
__device__ float g_bias[896];
__device__ float g_fcS[896];
__device__ float g_fcC[896];
__device__ float g_T0[2 * 64 * 64 * 64];
__device__ float g_T1[2 * 128 * 32 * 32];
__device__ float g_T2[2 * 256 * 16 * 16];

// ---- scalar helpers -------------------------------------------------------
__device__ __forceinline__ float ldf(const void* p, size_t i, int f32v) {
  return f32v ? ((const float*)p)[i] : __bfloat162float(((const bf16*)p)[i]);
}
template <bool F32>
__device__ __forceinline__ float ld(const void* p, size_t i) {
  if constexpr (F32) return ((const float*)p)[i];
  else return __bfloat162float(((const bf16*)p)[i]);
}
__device__ __forceinline__ void stf(void* p, size_t i, float v, int f32v) {
  if (f32v) ((float*)p)[i] = v;
  else ((bf16*)p)[i] = __float2bfloat16(v);
}
__device__ __forceinline__ int detect_f32(const void* extr) {
  float v = ((const float*)extr)[0];
  return (fabsf(v - 1.0f) < 0.25f) ? 1 : 0;
}

// hi/lo bf16 split: v ~= hi + lo, ~2^-16 relative error
__device__ __forceinline__ void splitbf(float v, u16& h, u16& l) {
  bf16 hb = __float2bfloat16(v);
  float hf = __bfloat162float(hb);
  bf16 lb = __float2bfloat16(v - hf);
  h = __builtin_bit_cast(u16, hb);
  l = __builtin_bit_cast(u16, lb);
}
__device__ __forceinline__ float bfjoin(u16 h, u16 l) {
  return __uint_as_float((u32)h << 16) + __uint_as_float((u32)l << 16);
}

// LDS activation tile [32][256] bf16, row stride 512B, XOR swizzle so
// 32-row column reads are bank-balanced.
__device__ __forceinline__ u16* xaddr(u16* base, int row, int col) {
  int byte = (row << 9) + (col << 1);
  byte ^= (row & 7) << 4;
  return (u16*)((char*)base + byte);
}
__device__ __forceinline__ const u16* xaddrc(const u16* base, int row, int col) {
  int byte = (row << 9) + (col << 1);
  byte ^= (row & 7) << 4;
  return (const u16*)((const char*)base + byte);
}

__device__ __forceinline__ f32x16 MFMA32(s8b a, s8b b, f32x16 c) {
  return __builtin_amdgcn_mfma_f32_32x32x16_bf16(a, b, c, 0, 0, 0);
}

// ---------------------------------------------------------------------------
// prep1: stats + P matrices + image transposes + non-fc weight/bias packing
// ---------------------------------------------------------------------------
template <bool F32>
__device__ void stats_body(const void* img0, const void* img1, const void* img2,
                           const void* intr, const void* extr,
                           float* wsf, float* red) {
  int bid = blockIdx.x;
  if (bid >= 896) {
    int b = bid - 896;
    int t = threadIdx.x;
    if (t < 12) {
      int r = t >> 2, c = t & 3;
      float acc = 0.f;
      for (int k = 0; k < 3; ++k)
        acc += ld<F32>(intr, b * 9 + r * 3 + k) * ld<F32>(extr, b * 12 + k * 4 + c);
      wsf[b * 12 + r * 4 + c] = acc;
    }
    return;
  }
  const void* src; size_t base; int HW, outidx;
  if (bid < 128) {
    int b = bid >> 6, c = bid & 63;
    src = img0; base = (size_t)(b * 64 + c) * 4096; HW = 4096;
    outidx = 32 + b * 64 + c;
  } else if (bid < 384) {
    int t = bid - 128; int b = t >> 7, c = t & 127;
    src = img1; base = (size_t)(b * 128 + c) * 1024; HW = 1024;
    outidx = 32 + 128 + b * 128 + c;
  } else {
    int t = bid - 384; int b = t >> 8, c = t & 255;
    src = img2; base = (size_t)(b * 256 + c) * 256; HW = 256;
    outidx = 32 + 384 + b * 256 + c;
  }
  float s1 = 0.f, s2 = 0.f;
  for (int i = threadIdx.x; i < HW; i += 256) {
    float v = ld<F32>(src, base + i);
    s1 += v; s2 += v * v;
  }
  for (int off = 32; off; off >>= 1) {
    s1 += __shfl_xor(s1, off);
    s2 += __shfl_xor(s2, off);
  }
  int wid = threadIdx.x >> 6, lane = threadIdx.x & 63;
  if (lane == 0) { red[wid] = s1; red[4 + wid] = s2; }
  __syncthreads();
  if (threadIdx.x == 0) {
    float S1 = red[0] + red[1] + red[2] + red[3];
    float S2 = red[4] + red[5] + red[6] + red[7];
    float mu = S1 / (float)HW;
    float var = (S2 - (float)HW * mu * mu) / (float)(HW - 1);
    var = fmaxf(var, 0.f);
    wsf[outidx] = mu;
    wsf[outidx + 896] = sqrtf(var + EPSF);
  }
}

__global__ __launch_bounds__(256) void prep1(
    const void* img0, const void* img1, const void* img2,
    const void* intr, const void* extr,
    const void* w1_0, const void* w2_0, const void* w1_1, const void* w2_1,
    const void* w1_2, const void* w2_2,
    const void* b1_0, const void* b2_0, const void* b1_1, const void* b2_1,
    const void* b1_2, const void* b2_2,
    float* wsf) {
  __shared__ float red[8];
  const int f32v = detect_f32(extr);
  int bid = blockIdx.x;
  int tid = threadIdx.x;

  if (bid < 898) {
    if (f32v) stats_body<true>(img0, img1, img2, intr, extr, wsf, red);
    else      stats_body<false>(img0, img1, img2, intr, extr, wsf, red);
    return;
  }
  if (bid < 4482) {  // transposes: coalesced read, scattered write
    const void* src; float* dst; int C, R, i0;
    if (bid < 2946)       { src = img0; dst = g_T0; C = 64;  R = 64; i0 = (bid - 898) * 256; }
    else if (bid < 3970)  { src = img1; dst = g_T1; C = 128; R = 32; i0 = (bid - 2946) * 256; }
    else                  { src = img2; dst = g_T2; C = 256; R = 16; i0 = (bid - 3970) * 256; }
    int i = i0 + tid;  // linear over (b,c,y,x), x fastest == src order
    int x = i % R; int t = i / R;
    int y = t % R; t /= R;
    int c = t % C; int b = t / C;
    dst[((size_t)(b * R + y) * R + x) * C + c] = ldf(src, i, f32v);
    return;
  }
  if (bid < 4607) {  // non-fc weight pack: 500 chunks
    int chunk = (bid - 4482) * 4 + (tid >> 6);
    int lane = tid & 63;
    if (chunk < 500) {
      const int nch[6]   = {4, 16, 32, 64, 128, 256};
      const int cbase[6] = {0, 4, 20, 52, 116, 244};
      const int couts[6] = {64, 64, 128, 128, 256, 256};
      const int kreal[6] = {3, 64, 64, 128, 128, 256};
      const void* wp[6] = {w1_0, w2_0, w1_1, w2_1, w1_2, w2_2};
      int layer = 5;
      for (int s = 0; s < 5; ++s) if (chunk < cbase[s + 1]) { layer = s; break; }
      int ci = chunk - cbase[layer];
      int COUT = couts[layer], KR = kreal[layer];
      int STR = COUT >> 5;
      int ks = ci / (STR * 2);
      int rem = ci % (STR * 2);
      int nt = rem >> 1, split = rem & 1;
      const void* W = wp[layer];
      s8b sv;
#pragma unroll
      for (int j = 0; j < 8; ++j) {
        int k = ks * 16 + 8 * (lane >> 5) + j;
        int c = nt * 32 + (lane & 31);
        float v = (k < KR) ? ldf(W, (size_t)k * COUT + c, f32v) : 0.f;
        u16 h, l; splitbf(v, h, l);
        sv[j] = (short)(split == 0 ? h : l);
      }
      *(s8b*)((char*)g_wpack + (size_t)chunk * 1024 + lane * 16) = sv;
    }
    return;
  }
  {  // bias pack: 896 values
    int t = (bid - 4607) * 256 + tid;
    if (t < 896) {
      const int off[7] = {0, 64, 128, 256, 384, 640, 896};
      const void* bp[6] = {b1_0, b2_0, b1_1, b2_1, b1_2, b2_2};
      int seg = 0;
      while (seg < 5 && t >= off[seg + 1]) ++seg;
      g_bias[t] = ldf(bp[seg], t - off[seg], f32v);
    }
  }
}

// ---------------------------------------------------------------------------
// prep2: fc' = diag(sigma)*fcw pack (per batch) + S/cvec fold vectors.
// Must run after prep1 (needs image stats in wsf).
// ---------------------------------------------------------------------------
__global__ __launch_bounds__(256) void prep2(
    const void* extr,
    const void* fcw_0, const void* fcw_1, const void* fcw_2,
    const void* fcb_0, const void* fcb_1, const void* fcb_2,
    const float* wsf) {
  const int f32v = detect_f32(extr);
  int bid = blockIdx.x;
  int tid = threadIdx.x;
  if (bid < 168) {  // 672 fc chunks
    int chunk = bid * 4 + (tid >> 6);
    int lane = tid & 63;
    int bb = chunk / 336;
    int ci = chunk % 336;
    int C, COUT, loff; const void* W;
    if (ci < 16)      { C = 64;  COUT = 64;  loff = 0;   W = fcw_0; }
    else if (ci < 80) { C = 128; COUT = 128; loff = 128; W = fcw_1; ci -= 16; }
    else              { C = 256; COUT = 256; loff = 384; W = fcw_2; ci -= 80; }
    int STR = COUT >> 5;
    int ks = ci / (STR * 2);
    int rem = ci % (STR * 2);
    int nt = rem >> 1, split = rem & 1;
    const float* sig = wsf + 928 + loff + bb * C;
    s8b sv;
#pragma unroll
    for (int j = 0; j < 8; ++j) {
      int k = ks * 16 + 8 * (lane >> 5) + j;
      int c = nt * 32 + (lane & 31);
      float v = sig[k] * ldf(W, (size_t)k * COUT + c, f32v);
      u16 h, l; splitbf(v, h, l);
      sv[j] = (short)(split == 0 ? h : l);
    }
    *(s8b*)((char*)g_fcpack + (size_t)chunk * 1024 + lane * 16) = sv;
    return;
  }
  {  // S/cvec: 6 blocks, (b, layer)
    int idx = bid - 168;
    if (idx >= 6) return;
    int bb = idx / 3, layer = idx % 3;
    int C, colbase, loff; const void* W; const void* fb;
    if (layer == 0)      { C = 64;  colbase = 0;   loff = 0;   W = fcw_0; fb = fcb_0; }
    else if (layer == 1) { C = 128; colbase = 64;  loff = 128; W = fcw_1; fb = fcb_1; }
    else                 { C = 256; colbase = 192; loff = 384; W = fcw_2; fb = fcb_2; }
    int j = tid;
    if (j >= C) return;
    const float* sig = wsf + 928 + loff + bb * C;
    const float* mean = wsf + 32 + loff + bb * C;
    float S = 0.f, Cv = 0.f;
    for (int c = 0; c < C; ++c) {
      float w = sig[c] * ldf(W, (size_t)c * C + j, f32v);
      S += w;
      Cv += mean[c] * w;
    }
    Cv += ldf(fb, j, f32v);
    g_fcS[bb * 448 + colbase + j] = S;
    g_fcC[bb * 448 + colbase + j] = Cv;
  }
}

// ---------------------------------------------------------------------------
// MFMA core: acc[NTW] (32x32 tiles) = X[32 x KS*16] @ W (+bias), hi/lo 3-MFMA
// ---------------------------------------------------------------------------
template <int KS, int COUT, int NTW, bool HASBIAS>
__device__ __forceinline__ void mm32(
    const u16* Xh_, const u16* Xl_, const char* wlane,
    const float* biasp, int nt0, int lane, f32x16* acc) {
#pragma unroll
  for (int n = 0; n < NTW; ++n) {
    float bv = HASBIAS ? biasp[(nt0 + n) * 32 + (lane & 31)] : 0.f;
#pragma unroll
    for (int q = 0; q < 16; ++q) acc[n][q] = bv;
  }
  const int rowA = lane & 31;
  const int acol = (lane >> 5) * 8;
#pragma unroll
  for (int ks = 0; ks < KS; ++ks) {
    s8b ah = *(const s8b*)xaddrc(Xh_, rowA, ks * 16 + acol);
    s8b al = *(const s8b*)xaddrc(Xl_, rowA, ks * 16 + acol);
#pragma unroll
    for (int n = 0; n < NTW; ++n) {
      const char* ch = wlane + (size_t)((ks * (COUT / 32) + nt0 + n) * 2) * 1024;
      s8b bh = *(const s8b*)(ch);
      s8b bl = *(const s8b*)(ch + 1024);
      acc[n] = MFMA32(ah, bh, acc[n]);
      acc[n] = MFMA32(ah, bl, acc[n]);
      acc[n] = MFMA32(al, bh, acc[n]);
    }
  }
}

template <int COUT>
__device__ __forceinline__ void strip_assign(int wid, int& nt0, int& active) {
  if constexpr (COUT == 64)      { nt0 = (wid & 1);  active = (wid < 2); }
  else if constexpr (COUT == 128){ nt0 = wid;        active = 1; }
  else                           { nt0 = wid * 2;    active = 1; }
}

// dense layer, in-place (mm -> sync -> writeback -> sync)
template <int KS, int COUT>
__device__ __forceinline__ void dense32(u16* Xh_, u16* Xl_,
                                        int wbyte, int bbase, int tid) {
  constexpr int NTW = (COUT == 256) ? 2 : 1;
  int lane = tid & 63, wid = tid >> 6;
  int nt0, active;
  strip_assign<COUT>(wid, nt0, active);
  f32x16 acc[NTW];
  if (active)
    mm32<KS, COUT, NTW, true>(Xh_, Xl_,
        (const char*)g_wpack + wbyte + lane * 16, g_bias + bbase, nt0, lane, acc);
  __syncthreads();
  if (active) {
    int g = lane >> 5;
#pragma unroll
    for (int n = 0; n < NTW; ++n) {
      int col = (nt0 + n) * 32 + (lane & 31);
#pragma unroll
      for (int q = 0; q < 16; ++q) {
        int row = (q & 3) + 8 * (q >> 2) + 4 * g;
        float v = fmaxf(acc[n][q], 0.f);
        u16 h, l; splitbf(v, h, l);
        *xaddr(Xh_, row, col) = h;
        *xaddr(Xl_, row, col) = l;
      }
    }
  }
  __syncthreads();
}

// per-row mean / inv-std over C (ddof=1), read-only on X
template <int C>
__device__ __forceinline__ void musig(const u16* Xh_, const u16* Xl_,
                                      int lane, float& mu, float& rs) {
  int row = lane & 31;
  int c0 = (lane >> 5) * (C / 2);
  float s1 = 0.f, s2 = 0.f;
#pragma unroll
  for (int k = 0; k < C / 2; k += 8) {
    s8b h = *(const s8b*)xaddrc(Xh_, row, c0 + k);
    s8b l = *(const s8b*)xaddrc(Xl_, row, c0 + k);
#pragma unroll
    for (int i = 0; i < 8; ++i) {
      float f = bfjoin((u16)h[i], (u16)l[i]);
      s1 += f; s2 += f * f;
    }
  }
  s1 += __shfl_xor(s1, 32);
  s2 += __shfl_xor(s2, 32);
  mu = s1 / (float)C;
  float var = (s2 - (float)C * mu * mu) / (float)(C - 1);
  var = fmaxf(var, 0.f);
  rs = 1.0f / sqrtf(var + EPSF);
}

// fc with AdaIN folded: out = rs*(x@W' - mu*S) + cvec. Read-only on X.
template <int KS, int COUT>
__device__ __forceinline__ void fc32(const u16* Xh_, const u16* Xl_,
    int fcbyte, int scbase, float mu, float rs,
    void* out, u32 R0, int colbase, int f32v, int tid) {
  constexpr int NTW = (COUT == 256) ? 2 : 1;
  int lane = tid & 63, wid = tid >> 6;
  int nt0, active;
  strip_assign<COUT>(wid, nt0, active);
  if (!active) return;
  f32x16 acc[NTW];
  mm32<KS, COUT, NTW, false>(Xh_, Xl_,
      (const char*)g_fcpack + fcbyte + lane * 16, nullptr, nt0, lane, acc);
  float Sv[NTW], Cv[NTW];
  u32 gcol[NTW];
#pragma unroll
  for (int n = 0; n < NTW; ++n) {
    int lc = (nt0 + n) * 32 + (lane & 31);
    Sv[n] = g_fcS[scbase + lc];
    Cv[n] = g_fcC[scbase + lc];
    gcol[n] = colbase + lc;
  }
  int g = lane >> 5;
  if (f32v) {
#pragma unroll
    for (int q = 0; q < 16; ++q) {
      int row = (q & 3) + 8 * (q >> 2) + 4 * g;
      float m = __shfl(mu, row);
      float r = __shfl(rs, row);
      u32 grow = (R0 + row) * 899u;
#pragma unroll
      for (int n = 0; n < NTW; ++n)
        ((float*)out)[grow + gcol[n]] = r * (acc[n][q] - m * Sv[n]) + Cv[n];
    }
  } else {
#pragma unroll
    for (int q = 0; q < 16; ++q) {
      int row = (q & 3) + 8 * (q >> 2) + 4 * g;
      float m = __shfl(mu, row);
      float r = __shfl(rs, row);
      u32 grow = (R0 + row) * 899u;
#pragma unroll
      for (int n = 0; n < NTW; ++n)
        ((bf16*)out)[grow + gcol[n]] =
            __float2bfloat16(r * (acc[n][q] - m * Sv[n]) + Cv[n]);
    }
  }
}

// ---- bilinear border sample -----------------------------------------------
template <int C, int R>
__device__ __forceinline__ void sample(
    const float* T, float u, float v, int b, int lane,
    void* out, u32 obase, int f32v) {
  constexpr int J = C / 64;
  float ix = fminf(fmaxf((u + 1.f) * 0.5f * (float)(R - 1), 0.f), (float)(R - 1));
  float iy = fminf(fmaxf((v + 1.f) * 0.5f * (float)(R - 1), 0.f), (float)(R - 1));
  float x0f = floorf(ix), y0f = floorf(iy);
  float wx = ix - x0f, wy = iy - y0f;
  int x0 = (int)x0f, y0 = (int)y0f;
  int x1 = min(x0 + 1, R - 1), y1 = min(y0 + 1, R - 1);
  float w00 = (1.f - wx) * (1.f - wy), w01 = wx * (1.f - wy);
  float w10 = (1.f - wx) * wy,         w11 = wx * wy;
  const float* T00 = T + (size_t)((b * R + y0) * R + x0) * C;
  const float* T01 = T + (size_t)((b * R + y0) * R + x1) * C;
  const float* T10 = T + (size_t)((b * R + y1) * R + x0) * C;
  const float* T11 = T + (size_t)((b * R + y1) * R + x1) * C;
  float sv[J];
#pragma unroll
  for (int j = 0; j < J; ++j) {
    int c = lane + 64 * j;
    sv[j] = T00[c] * w00 + T01[c] * w01 + T10[c] * w10 + T11[c] * w11;
  }
  if (f32v) {
#pragma unroll
    for (int j = 0; j < J; ++j)
      ((float*)out)[obase + lane + 64 * j] = sv[j];
  } else {
#pragma unroll
    for (int j = 0; j < J; ++j)
      ((bf16*)out)[obase + lane + 64 * j] = __float2bfloat16(sv[j]);
  }
}

__device__ void projection(const void* init_pc, const float* wsf, void* out,
                           u32 R0, int b, int f32v, int tid) {
  int lane = tid & 63, wid = tid >> 6;
  float Pm[12];
#pragma unroll
  for (int i = 0; i < 12; ++i) Pm[i] = wsf[b * 12 + i];
  for (int p = 0; p < 8; ++p) {
    u32 n = R0 + wid * 8 + p;
    float px = ldf(init_pc, (size_t)n * 3 + 0, f32v);
    float py = ldf(init_pc, (size_t)n * 3 + 1, f32v);
    float pz = ldf(init_pc, (size_t)n * 3 + 2, f32v);
    float X = Pm[0] * px + Pm[1] * py + Pm[2] * pz + Pm[3];
    float Y = Pm[4] * px + Pm[5] * py + Pm[6] * pz + Pm[7];
    float Z = Pm[8] * px + Pm[9] * py + Pm[10] * pz + Pm[11];
    float u = -X / Z, vv = Y / Z;
    u32 rowb = n * 899u;
    sample<64, 64>(g_T0, u, vv, b, lane, out, rowb + 448, f32v);
    sample<128, 32>(g_T1, u, vv, b, lane, out, rowb + 512, f32v);
    sample<256, 16>(g_T2, u, vv, b, lane, out, rowb + 640, f32v);
    if (lane < 3) {
      float pv = (lane == 0) ? px : (lane == 1) ? py : pz;
      stf(out, rowb + 896 + lane, pv, f32v);
    }
  }
}

// ---------------------------------------------------------------------------
// Main fused kernel: 32 points/block, 4 waves, 32x32x16 MFMA, single in-place
// LDS activation buffer (32 KiB) -> 5 blocks/CU.
// ---------------------------------------------------------------------------
__global__ __launch_bounds__(256, 5) void pce_main(
    const void* init_pc, const void* extr, const float* wsf, void* out) {
  __shared__ u16 Xh[8192];  // [32][256]
  __shared__ u16 Xl[8192];
  const int f32v = detect_f32(extr);
  const int tid = threadIdx.x;
  const int lane = tid & 63;
  const u32 R0 = blockIdx.x * 32;
  const int b = (int)(R0 >> 16);

  // zero K-pad region (cols 0..15, all rows), then stage pc into cols 0..2
  for (int i = tid; i < 512; i += 256) {
    int r = i >> 4, c = i & 15;
    *xaddr(Xh, r, c) = 0;
    *xaddr(Xl, r, c) = 0;
  }
  __syncthreads();
  if (tid < 96) {
    int r = tid / 3, c = tid % 3;
    float v = ldf(init_pc, (size_t)(R0 + r) * 3 + c, f32v);
    u16 h, l; splitbf(v, h, l);
    *xaddr(Xh, r, c) = h;
    *xaddr(Xl, r, c) = l;
  }
  __syncthreads();

  // block 0 (64ch)
  dense32<1, 64>(Xh, Xl, 0, 0, tid);
  dense32<4, 64>(Xh, Xl, 4096, 64, tid);
  { float mu, rs; musig<64>(Xh, Xl, lane, mu, rs);
    fc32<4, 64>(Xh, Xl, b * 344064 + 0, b * 448 + 0, mu, rs, out, R0, 0, f32v, tid); }

  // block 1 (128ch)  [fc0 reads precede dense's first sync -> in-place safe]
  dense32<4, 128>(Xh, Xl, 20480, 128, tid);
  dense32<8, 128>(Xh, Xl, 53248, 256, tid);
  { float mu, rs; musig<128>(Xh, Xl, lane, mu, rs);
    fc32<8, 128>(Xh, Xl, b * 344064 + 16384, b * 448 + 64, mu, rs, out, R0, 64, f32v, tid); }

  // block 2 (256ch)
  dense32<8, 256>(Xh, Xl, 118784, 384, tid);
  dense32<16, 256>(Xh, Xl, 249856, 640, tid);
  { float mu, rs; musig<256>(Xh, Xl, lane, mu, rs);
    fc32<16, 256>(Xh, Xl, b * 344064 + 81920, b * 448 + 192, mu, rs, out, R0, 192, f32v, tid); }

  // projections + passthrough
  projection(init_pc, wsf, out, R0, b, f32v, tid);
}

// ---------------------------------------------------------------------------
extern "C" void kernel_launch(void* const* d_in, const int* in_sizes, int n_in,
                              void* d_out, int out_size, void* d_ws, size_t ws_size,
                              hipStream_t stream) {
  const void* init_pc = d_in[0];
  const void* extr    = d_in[1];
  const void* intr    = d_in[2];
  const void* img0    = d_in[3];
  const void* img1    = d_in[4];
  const void* img2    = d_in[5];
  const void* w1_0 = d_in[6],  *b1_0 = d_in[7];
  const void* w2_0 = d_in[8],  *b2_0 = d_in[9];
  const void* fcw_0 = d_in[10], *fcb_0 = d_in[11];
  const void* w1_1 = d_in[12], *b1_1 = d_in[13];
  const void* w2_1 = d_in[14], *b2_1 = d_in[15];
  const void* fcw_1 = d_in[16], *fcb_1 = d_in[17];
  const void* w1_2 = d_in[18], *b1_2 = d_in[19];
  const void* w2_2 = d_in[20], *b2_2 = d_in[21];
  const void* fcw_2 = d_in[22], *fcb_2 = d_in[23];

  float* wsf = (float*)d_ws;

  // prep1: stats(898) | T0(2048) | T1(1024) | T2(512) | wpack(125) | bias(4)
  prep1<<<4611, 256, 0, stream>>>(
      img0, img1, img2, intr, extr,
      w1_0, w2_0, w1_1, w2_1, w1_2, w2_2,
      b1_0, b2_0, b1_1, b2_1, b1_2, b2_2, wsf);
  // prep2: fc' pack (168) + S/cvec (6); needs stats
  prep2<<<174, 256, 0, stream>>>(
      extr, fcw_0, fcw_1, fcw_2, fcb_0, fcb_1, fcb_2, wsf);
  pce_main<<<4096, 256, 0, stream>>>(init_pc, extr, wsf, d_out);
}

// Round 3
// 809.538 us; speedup vs baseline: 1.9792x; 1.1128x over previous
//
#include <hip/hip_runtime.h>
#include <hip/hip_bf16.h>

typedef __hip_bfloat16 bf16;
typedef unsigned short u16;
typedef unsigned int u32;
typedef __attribute__((ext_vector_type(8))) short s8b;     // 8 bf16 = 4 VGPR MFMA frag
typedef __attribute__((ext_vector_type(16))) float f32x16; // 32x32 MFMA accum

#define EPSF 1e-8f

// ---------------------------------------------------------------------------
// Static device buffers:
//   g_wpack : non-fc dense weights, bf16 hi/lo 32x32x16 B-fragments.
//   g_fcpack: fc' = diag(sigma_img)*fcw, per-batch (2 copies), same layout.
//   g_bias  : dense biases (896 f32). fc biases folded into g_fcC.
//   g_fcS   : [2][448] colsum(W')        (AdaIN fold)
//   g_fcC   : [2][448] imean@W' + fcb    (AdaIN fold)
//   g_T*    : images transposed to (b,y,x,c) f32.
// ---------------------------------------------------------------------------
__device__ __align__(16) u16 g_wpack[256000];   // 500 chunks * 512 u16
__device__ __align__(16) u16 g_fcpack[344064];  // 672 chunks
__device__ float g_bias[896];
__device__ float g_fcS[896];
__device__ float g_fcC[896];
__device__ float g_T0[2 * 64 * 64 * 64];
__device__ float g_T1[2 * 128 * 32 * 32];
__device__ float g_T2[2 * 256 * 16 * 16];

// ---- scalar helpers -------------------------------------------------------
__device__ __forceinline__ float ldf(const void* p, size_t i, int f32v) {
  return f32v ? ((const float*)p)[i] : __bfloat162float(((const bf16*)p)[i]);
}
template <bool F32>
__device__ __forceinline__ float ld(const void* p, size_t i) {
  if constexpr (F32) return ((const float*)p)[i];
  else return __bfloat162float(((const bf16*)p)[i]);
}
__device__ __forceinline__ int detect_f32(const void* extr) {
  float v = ((const float*)extr)[0];
  return (fabsf(v - 1.0f) < 0.25f) ? 1 : 0;
}

// hi/lo bf16 split: v ~= hi + lo, ~2^-16 relative error
__device__ __forceinline__ void splitbf(float v, u16& h, u16& l) {
  bf16 hb = __float2bfloat16(v);
  float hf = __bfloat162float(hb);
  bf16 lb = __float2bfloat16(v - hf);
  h = __builtin_bit_cast(u16, hb);
  l = __builtin_bit_cast(u16, lb);
}
__device__ __forceinline__ float bfjoin(u16 h, u16 l) {
  return __uint_as_float((u32)h << 16) + __uint_as_float((u32)l << 16);
}
__device__ __forceinline__ u16 f2bfu(float v) {
  return __builtin_bit_cast(u16, __float2bfloat16(v));
}

// LDS activation tile [32][256] bf16, row stride 512B, XOR swizzle.
__device__ __forceinline__ u16* xaddr(u16* base, int row, int col) {
  int byte = (row << 9) + (col << 1);
  byte ^= (row & 7) << 4;
  return (u16*)((char*)base + byte);
}
__device__ __forceinline__ const u16* xaddrc(const u16* base, int row, int col) {
  int byte = (row << 9) + (col << 1);
  byte ^= (row & 7) << 4;
  return (const u16*)((const char*)base + byte);
}

__device__ __forceinline__ f32x16 MFMA32(s8b a, s8b b, f32x16 c) {
  return __builtin_amdgcn_mfma_f32_32x32x16_bf16(a, b, c, 0, 0, 0);
}

// ---------------------------------------------------------------------------
// prep1: stats + P matrices + LDS-tiled image transposes + weight/bias pack
// ---------------------------------------------------------------------------
template <bool F32>
__device__ void stats_body(const void* img0, const void* img1, const void* img2,
                           const void* intr, const void* extr,
                           float* wsf, float* red) {
  int bid = blockIdx.x;
  if (bid >= 896) {
    int b = bid - 896;
    int t = threadIdx.x;
    if (t < 12) {
      int r = t >> 2, c = t & 3;
      float acc = 0.f;
      for (int k = 0; k < 3; ++k)
        acc += ld<F32>(intr, b * 9 + r * 3 + k) * ld<F32>(extr, b * 12 + k * 4 + c);
      wsf[b * 12 + r * 4 + c] = acc;
    }
    return;
  }
  const void* src; size_t base; int HW, outidx;
  if (bid < 128) {
    int b = bid >> 6, c = bid & 63;
    src = img0; base = (size_t)(b * 64 + c) * 4096; HW = 4096;
    outidx = 32 + b * 64 + c;
  } else if (bid < 384) {
    int t = bid - 128; int b = t >> 7, c = t & 127;
    src = img1; base = (size_t)(b * 128 + c) * 1024; HW = 1024;
    outidx = 32 + 128 + b * 128 + c;
  } else {
    int t = bid - 384; int b = t >> 8, c = t & 255;
    src = img2; base = (size_t)(b * 256 + c) * 256; HW = 256;
    outidx = 32 + 384 + b * 256 + c;
  }
  float s1 = 0.f, s2 = 0.f;
  for (int i = threadIdx.x; i < HW; i += 256) {
    float v = ld<F32>(src, base + i);
    s1 += v; s2 += v * v;
  }
  for (int off = 32; off; off >>= 1) {
    s1 += __shfl_xor(s1, off);
    s2 += __shfl_xor(s2, off);
  }
  int wid = threadIdx.x >> 6, lane = threadIdx.x & 63;
  if (lane == 0) { red[wid] = s1; red[4 + wid] = s2; }
  __syncthreads();
  if (threadIdx.x == 0) {
    float S1 = red[0] + red[1] + red[2] + red[3];
    float S2 = red[4] + red[5] + red[6] + red[7];
    float mu = S1 / (float)HW;
    float var = (S2 - (float)HW * mu * mu) / (float)(HW - 1);
    var = fmaxf(var, 0.f);
    wsf[outidx] = mu;
    wsf[outidx + 896] = sqrtf(var + EPSF);
  }
}

__global__ __launch_bounds__(256) void prep1(
    const void* img0, const void* img1, const void* img2,
    const void* intr, const void* extr,
    const void* w1_0, const void* w2_0, const void* w1_1, const void* w2_1,
    const void* w1_2, const void* w2_2,
    const void* b1_0, const void* b2_0, const void* b1_1, const void* b2_1,
    const void* b1_2, const void* b2_2,
    float* wsf) {
  __shared__ float red[8];
  __shared__ float tl[4352];  // up to 256*(16+1)
  const int f32v = detect_f32(extr);
  int bid = blockIdx.x;
  int tid = threadIdx.x;

  if (bid < 898) {
    if (f32v) stats_body<true>(img0, img1, img2, intr, extr, wsf, red);
    else      stats_body<false>(img0, img1, img2, intr, extr, wsf, red);
    return;
  }
  if (bid < 1122) {  // LDS-tiled transposes, one (b,y) plane per block
    int pl = bid - 898;
    const void* src; float* dst; int C, R, rsh, csh, b, y;
    if (pl < 128)      { src = img0; dst = g_T0; C = 64;  R = 64; rsh = 6; csh = 6; b = pl >> 6; y = pl & 63; }
    else if (pl < 192) { src = img1; dst = g_T1; C = 128; R = 32; rsh = 5; csh = 7; int q = pl - 128; b = q >> 5; y = q & 31; }
    else               { src = img2; dst = g_T2; C = 256; R = 16; rsh = 4; csh = 8; int q = pl - 192; b = q >> 4; y = q & 15; }
    int CR = C * R;
    for (int i = tid; i < CR; i += 256) {  // coalesced-ish read (full lines)
      int c = i >> rsh, x = i & (R - 1);
      tl[c * (R + 1) + x] = ldf(src, ((size_t)(b * C + c) * R + y) * R + x, f32v);
    }
    __syncthreads();
    for (int i = tid; i < CR; i += 256) {  // fully coalesced write
      int x = i >> csh, c = i & (C - 1);
      dst[((size_t)(b * R + y) * R + x) * C + c] = tl[c * (R + 1) + x];
    }
    return;
  }
  if (bid < 1247) {  // non-fc weight pack: 500 chunks
    int chunk = (bid - 1122) * 4 + (tid >> 6);
    int lane = tid & 63;
    if (chunk < 500) {
      const int cbase[6] = {0, 4, 20, 52, 116, 244};
      const int couts[6] = {64, 64, 128, 128, 256, 256};
      const int kreal[6] = {3, 64, 64, 128, 128, 256};
      const void* wp[6] = {w1_0, w2_0, w1_1, w2_1, w1_2, w2_2};
      int layer = 5;
      for (int s = 0; s < 5; ++s) if (chunk < cbase[s + 1]) { layer = s; break; }
      int ci = chunk - cbase[layer];
      int COUT = couts[layer], KR = kreal[layer];
      int STR = COUT >> 5;
      int ks = ci / (STR * 2);
      int rem = ci % (STR * 2);
      int nt = rem >> 1, split = rem & 1;
      const void* W = wp[layer];
      s8b sv;
#pragma unroll
      for (int j = 0; j < 8; ++j) {
        int k = ks * 16 + 8 * (lane >> 5) + j;
        int c = nt * 32 + (lane & 31);
        float v = (k < KR) ? ldf(W, (size_t)k * COUT + c, f32v) : 0.f;
        u16 h, l; splitbf(v, h, l);
        sv[j] = (short)(split == 0 ? h : l);
      }
      *(s8b*)((char*)g_wpack + (size_t)chunk * 1024 + lane * 16) = sv;
    }
    return;
  }
  {  // bias pack: 896 values
    int t = (bid - 1247) * 256 + tid;
    if (t < 896) {
      const int off[7] = {0, 64, 128, 256, 384, 640, 896};
      const void* bp[6] = {b1_0, b2_0, b1_1, b2_1, b1_2, b2_2};
      int seg = 0;
      while (seg < 5 && t >= off[seg + 1]) ++seg;
      g_bias[t] = ldf(bp[seg], t - off[seg], f32v);
    }
  }
}

// ---------------------------------------------------------------------------
// prep2: fc' = diag(sigma)*fcw pack (per batch) + S/cvec fold vectors.
// ---------------------------------------------------------------------------
__global__ __launch_bounds__(256) void prep2(
    const void* extr,
    const void* fcw_0, const void* fcw_1, const void* fcw_2,
    const void* fcb_0, const void* fcb_1, const void* fcb_2,
    const float* wsf) {
  const int f32v = detect_f32(extr);
  int bid = blockIdx.x;
  int tid = threadIdx.x;
  if (bid < 168) {  // 672 fc chunks
    int chunk = bid * 4 + (tid >> 6);
    int lane = tid & 63;
    int bb = chunk / 336;
    int ci = chunk % 336;
    int C, COUT, loff; const void* W;
    if (ci < 16)      { C = 64;  COUT = 64;  loff = 0;   W = fcw_0; }
    else if (ci < 80) { C = 128; COUT = 128; loff = 128; W = fcw_1; ci -= 16; }
    else              { C = 256; COUT = 256; loff = 384; W = fcw_2; ci -= 80; }
    int STR = COUT >> 5;
    int ks = ci / (STR * 2);
    int rem = ci % (STR * 2);
    int nt = rem >> 1, split = rem & 1;
    const float* sig = wsf + 928 + loff + bb * C;
    s8b sv;
#pragma unroll
    for (int j = 0; j < 8; ++j) {
      int k = ks * 16 + 8 * (lane >> 5) + j;
      int c = nt * 32 + (lane & 31);
      float v = sig[k] * ldf(W, (size_t)k * COUT + c, f32v);
      u16 h, l; splitbf(v, h, l);
      sv[j] = (short)(split == 0 ? h : l);
    }
    *(s8b*)((char*)g_fcpack + (size_t)chunk * 1024 + lane * 16) = sv;
    return;
  }
  {  // S/cvec: 6 blocks
    int idx = bid - 168;
    if (idx >= 6) return;
    int bb = idx / 3, layer = idx % 3;
    int C, colbase, loff; const void* W; const void* fb;
    if (layer == 0)      { C = 64;  colbase = 0;   loff = 0;   W = fcw_0; fb = fcb_0; }
    else if (layer == 1) { C = 128; colbase = 64;  loff = 128; W = fcw_1; fb = fcb_1; }
    else                 { C = 256; colbase = 192; loff = 384; W = fcw_2; fb = fcb_2; }
    int j = tid;
    if (j >= C) return;
    const float* sig = wsf + 928 + loff + bb * C;
    const float* mean = wsf + 32 + loff + bb * C;
    float S = 0.f, Cv = 0.f;
    for (int c = 0; c < C; ++c) {
      float w = sig[c] * ldf(W, (size_t)c * C + j, f32v);
      S += w;
      Cv += mean[c] * w;
    }
    Cv += ldf(fb, j, f32v);
    g_fcS[bb * 448 + colbase + j] = S;
    g_fcC[bb * 448 + colbase + j] = Cv;
  }
}

// ---------------------------------------------------------------------------
// MFMA core: acc[NTW] (32x32 tiles) = X[32 x KS*16] @ W (+bias), hi/lo 3-MFMA
// ---------------------------------------------------------------------------
template <int KS, int COUT, int NTW, bool HASBIAS>
__device__ __forceinline__ void mm32(
    const u16* Xh_, const u16* Xl_, const char* wlane,
    const float* biasp, int nt0, int lane, f32x16* acc) {
#pragma unroll
  for (int n = 0; n < NTW; ++n) {
    float bv = HASBIAS ? biasp[(nt0 + n) * 32 + (lane & 31)] : 0.f;
#pragma unroll
    for (int q = 0; q < 16; ++q) acc[n][q] = bv;
  }
  const int rowA = lane & 31;
  const int acol = (lane >> 5) * 8;
#pragma unroll
  for (int ks = 0; ks < KS; ++ks) {
    s8b ah = *(const s8b*)xaddrc(Xh_, rowA, ks * 16 + acol);
    s8b al = *(const s8b*)xaddrc(Xl_, rowA, ks * 16 + acol);
#pragma unroll
    for (int n = 0; n < NTW; ++n) {
      const char* ch = wlane + (size_t)((ks * (COUT / 32) + nt0 + n) * 2) * 1024;
      s8b bh = *(const s8b*)(ch);
      s8b bl = *(const s8b*)(ch + 1024);
      acc[n] = MFMA32(ah, bh, acc[n]);
      acc[n] = MFMA32(ah, bl, acc[n]);
      acc[n] = MFMA32(al, bh, acc[n]);
    }
  }
}

// dense layer, in-place (mm -> sync -> writeback -> sync)
template <int KS, int COUT>
__device__ __forceinline__ void dense32(u16* Xh_, u16* Xl_,
                                        int wbyte, int bbase, int tid) {
  constexpr int NTW = (COUT == 256) ? 2 : 1;
  int lane = tid & 63, wid = tid >> 6;
  int nt0, active;
  if constexpr (COUT == 64)      { nt0 = (wid & 1);  active = (wid < 2); }
  else if constexpr (COUT == 128){ nt0 = wid;        active = 1; }
  else                           { nt0 = wid * 2;    active = 1; }
  f32x16 acc[NTW];
  if (active)
    mm32<KS, COUT, NTW, true>(Xh_, Xl_,
        (const char*)g_wpack + wbyte + lane * 16, g_bias + bbase, nt0, lane, acc);
  __syncthreads();
  if (active) {
    int g = lane >> 5;
#pragma unroll
    for (int n = 0; n < NTW; ++n) {
      int col = (nt0 + n) * 32 + (lane & 31);
#pragma unroll
      for (int q = 0; q < 16; ++q) {
        int row = (q & 3) + 8 * (q >> 2) + 4 * g;
        float v = fmaxf(acc[n][q], 0.f);
        u16 h, l; splitbf(v, h, l);
        *xaddr(Xh_, row, col) = h;
        *xaddr(Xl_, row, col) = l;
      }
    }
  }
  __syncthreads();
}

// per-row mean / inv-std over C (ddof=1), read-only on X
template <int C>
__device__ __forceinline__ void musig(const u16* Xh_, const u16* Xl_,
                                      int lane, float& mu, float& rs) {
  int row = lane & 31;
  int c0 = (lane >> 5) * (C / 2);
  float s1 = 0.f, s2 = 0.f;
#pragma unroll
  for (int k = 0; k < C / 2; k += 8) {
    s8b h = *(const s8b*)xaddrc(Xh_, row, c0 + k);
    s8b l = *(const s8b*)xaddrc(Xl_, row, c0 + k);
#pragma unroll
    for (int i = 0; i < 8; ++i) {
      float f = bfjoin((u16)h[i], (u16)l[i]);
      s1 += f; s2 += f * f;
    }
  }
  s1 += __shfl_xor(s1, 32);
  s2 += __shfl_xor(s2, 32);
  mu = s1 / (float)C;
  float var = (s2 - (float)C * mu * mu) / (float)(C - 1);
  var = fmaxf(var, 0.f);
  rs = 1.0f / sqrtf(var + EPSF);
}

// ---- bilinear border sample into LDS staging ------------------------------
template <int C, int R>
__device__ __forceinline__ void sample_stg(
    const float* T, float u, float v, int b, int lane, float* stg) {
  constexpr int J = C / 64;
  float ix = fminf(fmaxf((u + 1.f) * 0.5f * (float)(R - 1), 0.f), (float)(R - 1));
  float iy = fminf(fmaxf((v + 1.f) * 0.5f * (float)(R - 1), 0.f), (float)(R - 1));
  float x0f = floorf(ix), y0f = floorf(iy);
  float wx = ix - x0f, wy = iy - y0f;
  int x0 = (int)x0f, y0 = (int)y0f;
  int x1 = min(x0 + 1, R - 1), y1 = min(y0 + 1, R - 1);
  float w00 = (1.f - wx) * (1.f - wy), w01 = wx * (1.f - wy);
  float w10 = (1.f - wx) * wy,         w11 = wx * wy;
  const float* T00 = T + (size_t)((b * R + y0) * R + x0) * C;
  const float* T01 = T + (size_t)((b * R + y0) * R + x1) * C;
  const float* T10 = T + (size_t)((b * R + y1) * R + x0) * C;
  const float* T11 = T + (size_t)((b * R + y1) * R + x1) * C;
#pragma unroll
  for (int j = 0; j < J; ++j) {
    int c = lane + 64 * j;
    stg[c] = T00[c] * w00 + T01[c] * w01 + T10[c] * w10 + T11[c] * w11;
  }
}

// ---------------------------------------------------------------------------
// Main fused kernel: 32 points/block, 4 waves, 32x32x16 MFMA.
// fc accumulators held in registers; after fc2 the LDS activation buffer is
// reused as an 8-row x 904-col f32 staging tile; each output row is written
// exactly once via contiguous nontemporal stores.
// ---------------------------------------------------------------------------
__global__ __launch_bounds__(256, 3) void pce_main(
    const void* init_pc, const void* extr, const float* wsf, void* out) {
  __shared__ __align__(16) u16 Xsh[16384];  // Xh = [0,8192), Xl = [8192,16384)
  u16* Xh = Xsh;
  u16* Xl = Xsh + 8192;
  const int f32v = detect_f32(extr);
  const int tid = threadIdx.x;
  const int lane = tid & 63;
  const int wid = tid >> 6;
  const int hi = lane >> 5;
  const int colc = lane & 31;
  const u32 R0 = blockIdx.x * 32;
  const int b = (int)(R0 >> 16);

  // zero K-pad region (cols 0..15, all rows), stage pc into cols 0..2
  for (int i = tid; i < 512; i += 256) {
    int r = i >> 4, c = i & 15;
    *xaddr(Xh, r, c) = 0;
    *xaddr(Xl, r, c) = 0;
  }
  __syncthreads();
  if (tid < 96) {
    int r = tid / 3, c = tid % 3;
    float v = ldf(init_pc, (size_t)(R0 + r) * 3 + c, f32v);
    u16 h, l; splitbf(v, h, l);
    *xaddr(Xh, r, c) = h;
    *xaddr(Xl, r, c) = l;
  }
  __syncthreads();

  float mu0, rs0, mu1, rs1, mu2, rs2;
  f32x16 a0[1], a1[1], a2[2];

  // ---- block 0 (64ch) ----
  dense32<1, 64>(Xh, Xl, 0, 0, tid);
  dense32<4, 64>(Xh, Xl, 4096, 64, tid);
  musig<64>(Xh, Xl, lane, mu0, rs0);
  if (wid < 2)
    mm32<4, 64, 1, false>(Xh, Xl,
        (const char*)g_fcpack + b * 344064 + 0 + lane * 16, nullptr, wid & 1, lane, a0);

  // ---- block 1 (128ch) ---- (fc reads precede next dense's first sync)
  dense32<4, 128>(Xh, Xl, 20480, 128, tid);
  dense32<8, 128>(Xh, Xl, 53248, 256, tid);
  musig<128>(Xh, Xl, lane, mu1, rs1);
  mm32<8, 128, 1, false>(Xh, Xl,
      (const char*)g_fcpack + b * 344064 + 16384 + lane * 16, nullptr, wid, lane, a1);

  // ---- block 2 (256ch) ----
  dense32<8, 256>(Xh, Xl, 118784, 384, tid);
  dense32<16, 256>(Xh, Xl, 249856, 640, tid);
  musig<256>(Xh, Xl, lane, mu2, rs2);
  mm32<16, 256, 2, false>(Xh, Xl,
      (const char*)g_fcpack + b * 344064 + 81920 + lane * 16, nullptr, wid * 2, lane, a2);

  __syncthreads();  // all LDS activation reads done; Xsh reusable as staging

  // preload per-wave fold constants and P matrix
  const int scb = b * 448;
  float S0 = 0.f, C0 = 0.f;
  if (wid < 2) { S0 = g_fcS[scb + wid * 32 + colc]; C0 = g_fcC[scb + wid * 32 + colc]; }
  float S1 = g_fcS[scb + 64 + wid * 32 + colc];
  float C1 = g_fcC[scb + 64 + wid * 32 + colc];
  float S2a = g_fcS[scb + 192 + wid * 64 + colc];
  float C2a = g_fcC[scb + 192 + wid * 64 + colc];
  float S2b = g_fcS[scb + 192 + wid * 64 + 32 + colc];
  float C2b = g_fcC[scb + 192 + wid * 64 + 32 + colc];
  float Pm[12];
#pragma unroll
  for (int i = 0; i < 12; ++i) Pm[i] = wsf[b * 12 + i];

  float* stg = (float*)Xsh;  // [8][904] f32 staging

#pragma unroll
  for (int g = 0; g < 4; ++g) {
    // --- fc deposits: q = 4g+qq -> local row qq + 4*hi ---
#pragma unroll
    for (int qq = 0; qq < 4; ++qq) {
      int q = 4 * g + qq;
      int lr = qq + 4 * hi;          // local row in group (0..7)
      int trow = 8 * g + lr;         // tile row (0..31) for mu/rs shfl
      float m0 = __shfl(mu0, trow), r0v = __shfl(rs0, trow);
      float m1 = __shfl(mu1, trow), r1v = __shfl(rs1, trow);
      float m2 = __shfl(mu2, trow), r2v = __shfl(rs2, trow);
      if (wid < 2)
        stg[lr * 904 + (wid * 32 + colc)] = r0v * (a0[0][q] - m0 * S0) + C0;
      stg[lr * 904 + 64 + wid * 32 + colc] = r1v * (a1[0][q] - m1 * S1) + C1;
      stg[lr * 904 + 192 + wid * 64 + colc] = r2v * (a2[0][q] - m2 * S2a) + C2a;
      stg[lr * 904 + 192 + wid * 64 + 32 + colc] = r2v * (a2[1][q] - m2 * S2b) + C2b;
    }
    // --- projection deposits: wave handles local rows 2*wid, 2*wid+1 ---
#pragma unroll
    for (int pp = 0; pp < 2; ++pp) {
      int lr = wid * 2 + pp;
      u32 n = R0 + 8 * g + lr;
      float px = ldf(init_pc, (size_t)n * 3 + 0, f32v);
      float py = ldf(init_pc, (size_t)n * 3 + 1, f32v);
      float pz = ldf(init_pc, (size_t)n * 3 + 2, f32v);
      float X = Pm[0] * px + Pm[1] * py + Pm[2] * pz + Pm[3];
      float Y = Pm[4] * px + Pm[5] * py + Pm[6] * pz + Pm[7];
      float Z = Pm[8] * px + Pm[9] * py + Pm[10] * pz + Pm[11];
      float u = -X / Z, vv = Y / Z;
      float* srow = stg + lr * 904;
      sample_stg<64, 64>(g_T0, u, vv, b, lane, srow + 448);
      sample_stg<128, 32>(g_T1, u, vv, b, lane, srow + 512);
      sample_stg<256, 16>(g_T2, u, vv, b, lane, srow + 640);
      if (lane < 3) srow[896 + lane] = (lane == 0) ? px : (lane == 1) ? py : pz;
    }
    __syncthreads();
    // --- flush 8 complete rows, contiguous, nontemporal ---
    u32 base = (R0 + 8 * g) * 899u;
    if (f32v) {
      float* op = (float*)out + base;
      for (int i = tid; i < 7192; i += 256) {
        u32 r = (u32)i / 899u;
        u32 c = (u32)i - r * 899u;
        __builtin_nontemporal_store(stg[r * 904 + c], op + i);
      }
    } else {
      u32* op = (u32*)out + (base >> 1);
      for (int i = tid; i < 3596; i += 256) {
        u32 e = (u32)i * 2;
        u32 r = e / 899u;
        u32 c = e - r * 899u;
        float v0 = stg[r * 904 + c];
        u32 r1 = (c + 1 == 899) ? r + 1 : r;
        u32 c1 = (c + 1 == 899) ? 0 : c + 1;
        float v1 = stg[r1 * 904 + c1];
        u32 pk = (u32)f2bfu(v0) | ((u32)f2bfu(v1) << 16);
        __builtin_nontemporal_store(pk, op + i);
      }
    }
    __syncthreads();
  }
}

// ---------------------------------------------------------------------------
extern "C" void kernel_launch(void* const* d_in, const int* in_sizes, int n_in,
                              void* d_out, int out_size, void* d_ws, size_t ws_size,
                              hipStream_t stream) {
  const void* init_pc = d_in[0];
  const void* extr    = d_in[1];
  const void* intr    = d_in[2];
  const void* img0    = d_in[3];
  const void* img1    = d_in[4];
  const void* img2    = d_in[5];
  const void* w1_0 = d_in[6],  *b1_0 = d_in[7];
  const void* w2_0 = d_in[8],  *b2_0 = d_in[9];
  const void* fcw_0 = d_in[10], *fcb_0 = d_in[11];
  const void* w1_1 = d_in[12], *b1_1 = d_in[13];
  const void* w2_1 = d_in[14], *b2_1 = d_in[15];
  const void* fcw_1 = d_in[16], *fcb_1 = d_in[17];
  const void* w1_2 = d_in[18], *b1_2 = d_in[19];
  const void* w2_2 = d_in[20], *b2_2 = d_in[21];
  const void* fcw_2 = d_in[22], *fcb_2 = d_in[23];

  float* wsf = (float*)d_ws;

  // prep1: stats(898) | transpose(224) | wpack(125) | bias(4)
  prep1<<<1251, 256, 0, stream>>>(
      img0, img1, img2, intr, extr,
      w1_0, w2_0, w1_1, w2_1, w1_2, w2_2,
      b1_0, b2_0, b1_1, b2_1, b1_2, b2_2, wsf);
  // prep2: fc' pack (168) + S/cvec (6); needs stats
  prep2<<<174, 256, 0, stream>>>(
      extr, fcw_0, fcw_1, fcw_2, fcb_0, fcb_1, fcb_2, wsf);
  pce_main<<<4096, 256, 0, stream>>>(init_pc, extr, wsf, d_out);
}